// Round 5
// baseline (566.860 us; speedup 1.0000x reference)
//
#include <hip/hip_runtime.h>
#include <math.h>

#define NN 100000
#define NE 3200000
#define INF_ 256
#define NH 8
#define OF 64
#define EF 64
#define NT 8

#define BSH 7                  // log2(nodes per bucket)
#define BNODES 128             // nodes per bucket
#define NB 782                 // ceil(NN/128)
#define CAPB 4608              // slots/bucket: Poisson(4096)+8 sigma
#define SPLIT 2                // sub-blocks per bucket in k_bucket_sum
#define CHUNK 2304             // CAPB/SPLIT (multiple of 128)
#define EPB 8192               // edges per k_partition block

// ws layout (float units). el separated from ers so the 3.2MB el table fits per-XCD L2;
// ers[n] = {er[0..7], s[0..7]} shares one 64B line (K4 gathers er+s in ONE line).
static constexpr size_t WS_AT      = 0;                        // 4096
static constexpr size_t WS_EE      = 4096;                     // 64
static constexpr size_t WS_EL      = 4160;                     // NN*8
static constexpr size_t WS_ERS     = WS_EL + (size_t)NN * 8;   // NN*16
static constexpr size_t WS_CCNT    = WS_ERS + (size_t)NN * 16; // NB
static constexpr size_t WS_PART    = WS_CCNT + NB + 2;         // NB*CAPB u32
static constexpr size_t WS_PARTIAL = WS_PART + (size_t)NB * CAPB; // NB*SPLIT*1024

// K1a: At[c][i] = sum_o W_fc[i, h*64+o]*attn[h,o]; c<8->attn_l, c>=8->attn_r. Zeroes ccnt.
__global__ __launch_bounds__(256) void k_prep_A(const float* __restrict__ W_fc,
                                                const float* __restrict__ attn_l,
                                                const float* __restrict__ attn_r,
                                                float* __restrict__ At,
                                                unsigned* __restrict__ ccnt) {
    int t = blockIdx.x * 256 + threadIdx.x;   // 0..4095
    if (t < NB) ccnt[t] = 0u;
    int c = t >> 8;
    int i = t & 255;
    int h = c & 7;
    const float* attn = (c < 8) ? attn_l : attn_r;
    const float* wrow = W_fc + (size_t)i * (NH * OF) + h * OF;
    const float* arow = attn + h * OF;
    float acc = 0.f;
#pragma unroll 8
    for (int o = 0; o < OF; ++o) acc += wrow[o] * arow[o];
    At[c * INF_ + i] = acc;
}

// K1b: ee_tab[t][h]
__global__ __launch_bounds__(512) void k_prep_ee(const float* __restrict__ edge_emb,
                                                 const float* __restrict__ W_e,
                                                 const float* __restrict__ attn_e,
                                                 float* __restrict__ ee_tab) {
    __shared__ float B[EF][NH];
    int t = threadIdx.x;
    int g = t >> 3, h = t & 7;
    const float* wrow = W_e + (size_t)g * (NH * EF) + h * EF;
    const float* arow = attn_e + h * EF;
    float acc = 0.f;
#pragma unroll 8
    for (int f = 0; f < EF; ++f) acc += wrow[f] * arow[f];
    B[g][h] = acc;
    __syncthreads();
    if (t < NT * NH) {
        int tt = t >> 3, hh = t & 7;
        float a = 0.f;
#pragma unroll 8
        for (int g2 = 0; g2 < EF; ++g2) a += edge_emb[tt * EF + g2] * B[g2][hh];
        ee_tab[tt * NH + hh] = a;
    }
}

// K2: el[n][h], ers[n][0..7]=er
__global__ __launch_bounds__(256) void k_node(const float* __restrict__ feat,
                                              const float* __restrict__ At,
                                              float* __restrict__ el,
                                              float* __restrict__ ers) {
    int n = blockIdx.x * 256 + threadIdx.x;
    if (n >= NN) return;
    const float4* f4 = (const float4*)(feat + (size_t)n * INF_);
    const float4* A4 = (const float4*)At;
    float acc[16];
#pragma unroll
    for (int c = 0; c < 16; ++c) acc[c] = 0.f;
    for (int iq = 0; iq < INF_ / 4; ++iq) {
        float4 f = f4[iq];
#pragma unroll
        for (int c = 0; c < 16; ++c) {
            float4 a = A4[c * 64 + iq];
            acc[c] += f.x * a.x + f.y * a.y + f.z * a.z + f.w * a.w;
        }
    }
    float4* e4 = (float4*)(el + (size_t)n * 8);
    e4[0] = make_float4(acc[0], acc[1], acc[2], acc[3]);
    e4[1] = make_float4(acc[4], acc[5], acc[6], acc[7]);
    float4* r4 = (float4*)(ers + (size_t)n * 16);
    r4[0] = make_float4(acc[8], acc[9], acc[10], acc[11]);
    r4[1] = make_float4(acc[12], acc[13], acc[14], acc[15]);
}

// K3a: partition into NB buckets. EPB=8192 -> ~306K global reserve atomics.
__global__ __launch_bounds__(256) void k_partition(const int* __restrict__ src,
                                                   const int* __restrict__ dst,
                                                   const int* __restrict__ etype,
                                                   unsigned* __restrict__ ccnt,
                                                   unsigned* __restrict__ part) {
    __shared__ unsigned hist[NB];
    __shared__ unsigned cursor[NB];
    int tid = threadIdx.x;
    size_t base = (size_t)blockIdx.x * EPB;
    unsigned long long rc[32];
    for (int i = tid; i < NB; i += 256) hist[i] = 0u;
    __syncthreads();
#pragma unroll
    for (int k = 0; k < 32; ++k) {
        size_t j = base + (size_t)k * 256 + tid;
        if (j < NE) {
            int dj = dst[j];
            rc[k] = (unsigned long long)(unsigned)src[j]
                  | ((unsigned long long)(unsigned)etype[j] << 17)
                  | ((unsigned long long)(unsigned)dj << 20);
            atomicAdd(&hist[dj >> BSH], 1u);
        } else rc[k] = ~0ull;
    }
    __syncthreads();
    for (int i = tid; i < NB; i += 256) {
        unsigned h = hist[i];
        cursor[i] = h ? atomicAdd(ccnt + i, h) : 0u;
    }
    __syncthreads();
#pragma unroll
    for (int k = 0; k < 32; ++k) {
        if (rc[k] == ~0ull) continue;
        int dj = (int)(rc[k] >> 20);
        int b = dj >> BSH;
        unsigned pos = atomicAdd(&cursor[b], 1u);
        if (pos < CAPB)
            part[(size_t)b * CAPB + pos] =
                (unsigned)(rc[k] & 0xFFFFFull) | ((unsigned)(dj & (BNODES - 1)) << 20);
    }
}

// K3b: per-sub-bucket sum. Edge-quad per 8-lane group: uint4 rec load (16B),
// software-pipelined one iteration ahead so the ~900cy cross-XCD rec miss
// overlaps the 4 independent el gathers + exp of the current quad.
__global__ __launch_bounds__(256) void k_bucket_sum(const unsigned* __restrict__ part,
                                                    const unsigned* __restrict__ ccnt,
                                                    const float* __restrict__ el,
                                                    const float* __restrict__ ers,
                                                    const float* __restrict__ ee_tab,
                                                    float* __restrict__ partial) {
    __shared__ float sbin[BNODES * 9];
    __shared__ float er_l[BNODES * 9];
    __shared__ float ee_l[NT * NH];
    int bs = blockIdx.x;
    int b = bs >> 1, c = bs & 1;
    int tid = threadIdx.x;
    int eq = tid >> 3;        // 0..31 edge-quad id
    int h  = tid & 7;
    int n0 = b << BSH;
    int nn = NN - n0; if (nn > BNODES) nn = BNODES;

    for (int i = tid; i < BNODES * 9; i += 256) sbin[i] = 0.f;
    if (tid < NT * NH) ee_l[tid] = ee_tab[tid];
    for (int i = tid; i < nn * NH; i += 256) {
        int nl = i >> 3, hh = i & 7;
        er_l[nl * 9 + hh] = ers[(size_t)(n0 + nl) * 16 + hh];
    }
    __syncthreads();

    unsigned cnt = ccnt[b]; if (cnt > CAPB) cnt = CAPB;
    unsigned lo = (unsigned)c * CHUNK;
    unsigned hi = lo + CHUNK; if (hi > cnt) hi = cnt;
    const unsigned* pp = part + (size_t)b * CAPB;

    if (lo < hi) {
        // guarded quad load: e is 16B-aligned (lo mult of 128, eq*4)
        auto load4 = [&](unsigned base_e) {
            unsigned e = base_e + 4u * eq;
            uint4 r = make_uint4(0u, 0u, 0u, 0u);
            if (e + 3 < hi) r = *(const uint4*)(pp + e);
            else {
                if (e     < hi) r.x = pp[e];
                if (e + 1 < hi) r.y = pp[e + 1];
                if (e + 2 < hi) r.z = pp[e + 2];
                if (e + 3 < hi) r.w = pp[e + 3];
            }
            return r;
        };
        uint4 r = load4(lo);
        for (unsigned base = lo; base < hi; base += 128) {
            uint4 rn;
            bool more = (base + 128 < hi);
            if (more) rn = load4(base + 128);
            unsigned e = base + 4u * eq;
            unsigned recs[4] = {r.x, r.y, r.z, r.w};
            float vv[4];
#pragma unroll
            for (int k = 0; k < 4; ++k) {
                if (e + k < hi) {
                    int sj = (int)(recs[k] & 0x1FFFFu);
                    vv[k] = el[(size_t)sj * 8 + h];
                }
            }
#pragma unroll
            for (int k = 0; k < 4; ++k) {
                if (e + k < hi) {
                    int et = (int)((recs[k] >> 17) & 7u);
                    int dl = (int)((recs[k] >> 20) & (BNODES - 1));
                    float v = vv[k] + er_l[dl * 9 + h] + ee_l[et * NH + h];
                    atomicAdd(&sbin[dl * 9 + h], expf(fmaxf(v, 0.f)));
                }
            }
            r = rn;
        }
    }
    __syncthreads();
    float* po = partial + ((size_t)b * SPLIT + c) * (BNODES * NH);
    for (int i = tid; i < nn * NH; i += 256)
        po[i] = sbin[(i >> 3) * 9 + (i & 7)];
}

// K3c: s[n][h] = sum_c partial[b][c][nl][h]  -> ers cols 8..15
__global__ __launch_bounds__(256) void k_reduce(const float* __restrict__ partial,
                                                float* __restrict__ ers) {
    int t = blockIdx.x * 256 + threadIdx.x;
    if (t >= NN * NH) return;
    int n = t >> 3, h = t & 7;
    int b = n >> BSH, nl = n & (BNODES - 1);
    const float* pa = partial + (size_t)b * SPLIT * (BNODES * NH);
    ers[(size_t)n * 16 + 8 + h] = pa[nl * NH + h] + pa[BNODES * NH + nl * NH + h];
}

// K4: 2 edges/thread; 4 independent gathers in flight (el 32B line + ers 64B line per edge).
__global__ __launch_bounds__(256) void k_edge_out(const int* __restrict__ src,
                                                  const int* __restrict__ dst,
                                                  const int* __restrict__ etype,
                                                  const float* __restrict__ el,
                                                  const float* __restrict__ ers,
                                                  const float* __restrict__ ee_tab,
                                                  float* __restrict__ out) {
    int j0 = (blockIdx.x * 256 + threadIdx.x) * 2;
    if (j0 + 1 >= NE) {
        if (j0 >= NE) return;
        // (NE is even; unreachable, kept for safety)
    }
    int2 sj = *(const int2*)(src + j0);
    int2 dj = *(const int2*)(dst + j0);
    int2 tj = *(const int2*)(etype + j0);
    const float4* elA = (const float4*)(el + (size_t)sj.x * 8);
    const float4* elB = (const float4*)(el + (size_t)sj.y * 8);
    const float4* EA  = (const float4*)(ers + (size_t)dj.x * 16);
    const float4* EB  = (const float4*)(ers + (size_t)dj.y * 16);
    float4 la0 = elA[0], la1 = elA[1];
    float4 lb0 = elB[0], lb1 = elB[1];
    float4 ra0 = EA[0], ra1 = EA[1], sa0 = EA[2], sa1 = EA[3];
    float4 rb0 = EB[0], rb1 = EB[1], sb0 = EB[2], sb1 = EB[3];
    const float4* eeA = (const float4*)(ee_tab + tj.x * NH);
    const float4* eeB = (const float4*)(ee_tab + tj.y * NH);
    float4 ea0 = eeA[0], ea1 = eeA[1];
    float4 eb0 = eeB[0], eb1 = eeB[1];
    float4 o0, o1, o2, o3;
    o0.x = expf(fmaxf(la0.x + ra0.x + ea0.x, 0.f)) / sa0.x;
    o0.y = expf(fmaxf(la0.y + ra0.y + ea0.y, 0.f)) / sa0.y;
    o0.z = expf(fmaxf(la0.z + ra0.z + ea0.z, 0.f)) / sa0.z;
    o0.w = expf(fmaxf(la0.w + ra0.w + ea0.w, 0.f)) / sa0.w;
    o1.x = expf(fmaxf(la1.x + ra1.x + ea1.x, 0.f)) / sa1.x;
    o1.y = expf(fmaxf(la1.y + ra1.y + ea1.y, 0.f)) / sa1.y;
    o1.z = expf(fmaxf(la1.z + ra1.z + ea1.z, 0.f)) / sa1.z;
    o1.w = expf(fmaxf(la1.w + ra1.w + ea1.w, 0.f)) / sa1.w;
    o2.x = expf(fmaxf(lb0.x + rb0.x + eb0.x, 0.f)) / sb0.x;
    o2.y = expf(fmaxf(lb0.y + rb0.y + eb0.y, 0.f)) / sb0.y;
    o2.z = expf(fmaxf(lb0.z + rb0.z + eb0.z, 0.f)) / sb0.z;
    o2.w = expf(fmaxf(lb0.w + rb0.w + eb0.w, 0.f)) / sb0.w;
    o3.x = expf(fmaxf(lb1.x + rb1.x + eb1.x, 0.f)) / sb1.x;
    o3.y = expf(fmaxf(lb1.y + rb1.y + eb1.y, 0.f)) / sb1.y;
    o3.z = expf(fmaxf(lb1.z + rb1.z + eb1.z, 0.f)) / sb1.z;
    o3.w = expf(fmaxf(lb1.w + rb1.w + eb1.w, 0.f)) / sb1.w;
    float4* o4 = (float4*)(out + (size_t)j0 * NH);
    o4[0] = o0; o4[1] = o1; o4[2] = o2; o4[3] = o3;
}

extern "C" void kernel_launch(void* const* d_in, const int* in_sizes, int n_in,
                              void* d_out, int out_size, void* d_ws, size_t ws_size,
                              hipStream_t stream) {
    const float* feat     = (const float*)d_in[0];
    const int*   etype    = (const int*)d_in[1];
    const int*   src      = (const int*)d_in[2];
    const int*   dst      = (const int*)d_in[3];
    const float* W_fc     = (const float*)d_in[4];
    const float* edge_emb = (const float*)d_in[5];
    const float* W_e      = (const float*)d_in[6];
    const float* attn_l   = (const float*)d_in[7];
    const float* attn_r   = (const float*)d_in[8];
    const float* attn_e   = (const float*)d_in[9];

    float*    ws      = (float*)d_ws;
    float*    At      = ws + WS_AT;
    float*    ee_tab  = ws + WS_EE;
    float*    el      = ws + WS_EL;
    float*    ers     = ws + WS_ERS;
    unsigned* ccnt    = (unsigned*)(ws + WS_CCNT);
    unsigned* part    = (unsigned*)(ws + WS_PART);
    float*    partial = ws + WS_PARTIAL;
    float*    out     = (float*)d_out;

    hipLaunchKernelGGL(k_prep_A, dim3(16), dim3(256), 0, stream, W_fc, attn_l, attn_r, At, ccnt);
    hipLaunchKernelGGL(k_prep_ee, dim3(1), dim3(512), 0, stream, edge_emb, W_e, attn_e, ee_tab);
    hipLaunchKernelGGL(k_node, dim3((NN + 255) / 256), dim3(256), 0, stream, feat, At, el, ers);
    hipLaunchKernelGGL(k_partition, dim3((NE + EPB - 1) / EPB), dim3(256), 0, stream,
                       src, dst, etype, ccnt, part);
    hipLaunchKernelGGL(k_bucket_sum, dim3(NB * SPLIT), dim3(256), 0, stream,
                       part, ccnt, el, ers, ee_tab, partial);
    hipLaunchKernelGGL(k_reduce, dim3((NN * NH + 255) / 256), dim3(256), 0, stream,
                       partial, ers);
    hipLaunchKernelGGL(k_edge_out, dim3(NE / 512, 1, 1), dim3(256), 0, stream,
                       src, dst, etype, el, ers, ee_tab, out);
}